// Round 5
// baseline (916.971 us; speedup 1.0000x reference)
//
#include <hip/hip_runtime.h>
#include <cstdint>

#define NN 20000
#define TT 256
#define EE 320000
#define GG 64
#define EMBD 768
#define FIND 512

typedef __bf16 bf16x8 __attribute__((ext_vector_type(8)));
typedef float f32x4 __attribute__((ext_vector_type(4)));

__device__ __forceinline__ float b2f(unsigned short u) {
  union { unsigned int i; float f; } v; v.i = ((unsigned int)u) << 16; return v.f;
}
__device__ __forceinline__ float b2f_lo(unsigned int u) {
  union { unsigned int i; float f; } v; v.i = u << 16; return v.f;
}
__device__ __forceinline__ float b2f_hi(unsigned int u) {
  union { unsigned int i; float f; } v; v.i = u & 0xFFFF0000u; return v.f;
}
__device__ __forceinline__ unsigned short f2bf(float f) {
  union { float f; unsigned int i; } v; v.f = f;
  unsigned int u = v.i;
  return (unsigned short)((u + 0x7FFFu + ((u >> 16) & 1u)) >> 16);
}
__device__ __forceinline__ unsigned int pack2bf(float lo, float hi) {
  return (unsigned int)f2bf(lo) | ((unsigned int)f2bf(hi) << 16);
}

// async global->LDS, 16B per lane. LDS dest is wave-uniform base + lane*16.
__device__ __forceinline__ void gload_lds16(const void* g, void* l) {
  auto gp = reinterpret_cast<const __attribute__((address_space(1))) char*>(
      reinterpret_cast<uintptr_t>(g));
  auto lp = reinterpret_cast<__attribute__((address_space(3))) char*>(
      (unsigned int)(reinterpret_cast<uintptr_t>(l)));
  __builtin_amdgcn_global_load_lds(gp, lp, 16, 0, 0);
}

// swizzled chunk offset: 16B pad every 8 chunks. Lanes l and l+8 land 4 banks
// apart -> stride-4-float patterns become conflict-free; 16B alignment kept.
__device__ __forceinline__ int sw16(int m) { return 16 * m + 16 * (m >> 3); }

// ---------------- fused temporal conv stack: x(N,256) -> h0 bf16 (N,512) ----
// 1 wave = 1 node, 4 nodes/block, 4 t per lane. Weights via uniform s_load.
// Register-pressure-aware: dv[8] (conv1 out) in 32 regs, conv2 k-outer so the
// 64-float p array never materializes. All LDS traffic swizzled b128.
__global__ __launch_bounds__(256, 3) void k_conv(
    const float* __restrict__ x,
    const float* __restrict__ w0, const float* __restrict__ g0,
    const float* __restrict__ be0, const float* __restrict__ mu0,
    const float* __restrict__ va0,
    const float* __restrict__ w1, const float* __restrict__ w2,
    const float* __restrict__ g2, const float* __restrict__ be2,
    const float* __restrict__ mu2, const float* __restrict__ va2,
    unsigned short* __restrict__ out) {
  __shared__ __align__(16) char xs[4][1280];     // chunk q: t = 4q-16, q in [0,71]
  __shared__ __align__(16) char hs[4][8][1280];  // chunk r: t = 4r-12, r in [0,71]
  const int tid = threadIdx.x;
  const int wv = tid >> 6;
  const int l = tid & 63;            // handles t = 4l .. 4l+3
  const int n = blockIdx.x * 4 + wv;

  float4 z4 = make_float4(0.f, 0.f, 0.f, 0.f);
  // stage x: lane l writes chunk l+4 (t=4l..4l+3); halos q in [0,3] & [68,71]
  *(float4*)(xs[wv] + sw16(l + 4)) = *(const float4*)(x + (size_t)n * TT + 4 * l);
  if (l < 4) *(float4*)(xs[wv] + sw16(l)) = z4;
  else if (l < 8) *(float4*)(xs[wv] + sw16(64 + l)) = z4;
  __syncthreads();

  // conv0 window: t = 4l-16 .. 4l+19 -> chunks l..l+8; win[idx] = x[4l-16+idx]
  float win[36];
  #pragma unroll
  for (int i = 0; i < 9; ++i)
    *(float4*)&win[4 * i] = *(const float4*)(xs[wv] + sw16(l + i));

  // conv0 (k=33, 1->8) + bn0 -> hs (channel at a time; c0 transient)
  #pragma unroll
  for (int c = 0; c < 8; ++c) {
    float s = g0[c] * rsqrtf(va0[c] + 1e-5f);
    float o = be0[c] - mu0[c] * s;
    float a0 = 0.f, a1 = 0.f, a2 = 0.f, a3 = 0.f;
    #pragma unroll
    for (int w = 0; w < 33; ++w) {
      float wt = w0[w * 8 + c];
      a0 += win[w] * wt; a1 += win[w + 1] * wt;
      a2 += win[w + 2] * wt; a3 += win[w + 3] * wt;
    }
    float4 v = make_float4(a0 * s + o, a1 * s + o, a2 * s + o, a3 * s + o);
    *(float4*)(hs[wv][c] + sw16(l + 3)) = v;   // chunk l+3: t=4l..4l+3
  }
  // halos: r in [0,2] (t=-12..-1) and r in [67,71] (t=256..275)
  if (l < 3) {
    #pragma unroll
    for (int c = 0; c < 8; ++c) *(float4*)(hs[wv][c] + sw16(l)) = z4;
  } else if (l < 8) {
    #pragma unroll
    for (int c = 0; c < 8; ++c) *(float4*)(hs[wv][c] + sw16(64 + l)) = z4;
  }
  __syncthreads();

  // conv1 depthwise (k=21) + relu -> dv[8] (32 regs)
  // window: t = 4l-12 .. 4l+15 -> chunks l..l+6; hw[idx] = h[4l-12+idx]
  float4 dv[8];
  #pragma unroll
  for (int c = 0; c < 8; ++c) {
    float hw[28];
    #pragma unroll
    for (int i = 0; i < 7; ++i)
      *(float4*)&hw[4 * i] = *(const float4*)(hs[wv][c] + sw16(l + i));
    float a0 = 0.f, a1 = 0.f, a2 = 0.f, a3 = 0.f;
    #pragma unroll
    for (int w = 0; w < 21; ++w) {
      float wt = w1[w * 8 + c];
      a0 += hw[w + 2] * wt; a1 += hw[w + 3] * wt;
      a2 += hw[w + 4] * wt; a3 += hw[w + 5] * wt;
    }
    dv[c] = make_float4(fmaxf(a0, 0.f), fmaxf(a1, 0.f),
                        fmaxf(a2, 0.f), fmaxf(a3, 0.f));
  }

  // conv2 pointwise (8->16) + bn2 + relu + mean-pool(8); k-outer, p transient
  float pool[16];
  #pragma unroll
  for (int k = 0; k < 16; ++k) {
    float s = g2[k] * rsqrtf(va2[k] + 1e-5f);
    float o = be2[k] - mu2[k] * s;
    float p0 = 0.f, p1 = 0.f, p2 = 0.f, p3 = 0.f;
    #pragma unroll
    for (int c = 0; c < 8; ++c) {
      float wt = w2[c * 16 + k];
      p0 += dv[c].x * wt; p1 += dv[c].y * wt;
      p2 += dv[c].z * wt; p3 += dv[c].w * wt;
    }
    float v = fmaxf(p0 * s + o, 0.f) + fmaxf(p1 * s + o, 0.f) +
              fmaxf(p2 * s + o, 0.f) + fmaxf(p3 * s + o, 0.f);
    v += __shfl_xor(v, 1);
    pool[k] = v * 0.125f;
  }
  if ((l & 1) == 0) {
    int grp = l >> 1;  // pool group 0..31
    unsigned short* op = out + (size_t)n * FIND + grp * 16;
    #pragma unroll
    for (int q = 0; q < 4; ++q) {
      ushort4 v;
      v.x = f2bf(pool[q * 4 + 0]); v.y = f2bf(pool[q * 4 + 1]);
      v.z = f2bf(pool[q * 4 + 2]); v.w = f2bf(pool[q * 4 + 3]);
      *(ushort4*)(op + q * 4) = v;
    }
  }
}

// ---------------- CSR build -------------------------------------------------
__global__ void k_count(const int* __restrict__ ei, int* __restrict__ deg) {
  int e = blockIdx.x * 256 + threadIdx.x;
  if (e < EE) atomicAdd(&deg[ei[EE + e]], 1);
}

// shfl-based scan: 4 barriers/iter instead of 20
__global__ __launch_bounds__(1024) void k_scan(const int* __restrict__ deg,
                                               int* __restrict__ row_ptr,
                                               int* __restrict__ cursor, int n) {
  __shared__ int wsums[16];
  __shared__ int carry_s;
  int tid = threadIdx.x, lane = tid & 63, wid = tid >> 6;
  if (tid == 0) carry_s = 0;
  __syncthreads();
  for (int base = 0; base < n; base += 1024) {
    int v = (base + tid < n) ? deg[base + tid] : 0;
    int inc = v;
    #pragma unroll
    for (int off = 1; off < 64; off <<= 1) {
      int t = __shfl_up(inc, off);
      if (lane >= off) inc += t;
    }
    if (lane == 63) wsums[wid] = inc;
    __syncthreads();
    if (wid == 0) {
      int s = (lane < 16) ? wsums[lane] : 0;
      #pragma unroll
      for (int off = 1; off < 16; off <<= 1) {
        int t = __shfl_up(s, off);
        if (lane >= off) s += t;
      }
      if (lane < 16) wsums[lane] = s;  // inclusive wave-sum prefix
    }
    __syncthreads();
    int woff = (wid > 0) ? wsums[wid - 1] : 0;
    int excl = carry_s + woff + inc - v;
    if (base + tid < n) { row_ptr[base + tid] = excl; cursor[base + tid] = excl; }
    __syncthreads();
    if (tid == 0) carry_s += wsums[15];
    __syncthreads();
  }
  if (tid == 0) row_ptr[n] = carry_s;
}

__global__ void k_scatter(const int* __restrict__ ei, int* __restrict__ cursor,
                          int* __restrict__ csr_src) {
  int e = blockIdx.x * 256 + threadIdx.x;
  if (e < EE) {
    int d = ei[EE + e];
    int pos = atomicAdd(&cursor[d], 1);
    csr_src[pos] = ei[e];
  }
}

// ---------------- merged weight transpose+convert (all 4 GIN weights) -------
__global__ void k_trans_all(const float* __restrict__ g1w1, const float* __restrict__ g1w2,
                            const float* __restrict__ g2w1, const float* __restrict__ g2w2,
                            unsigned short* __restrict__ w1T, unsigned short* __restrict__ w2T,
                            unsigned short* __restrict__ w3T, unsigned short* __restrict__ w4T) {
  int i = blockIdx.x * 256 + threadIdx.x;
  if (i < 393216) {                       // 768 x 512 (K=512)
    int nrow = i >> 9, k = i & 511;
    w1T[i] = f2bf(g1w1[(size_t)k * 768 + nrow]);
  } else {
    int j = i - 393216;
    int which = j / 589824;               // 0..2, 768 x 768 each
    int r = j - which * 589824;
    int nrow = r / 768, k = r - nrow * 768;
    const float* src = which == 0 ? g1w2 : (which == 1 ? g2w1 : g2w2);
    unsigned short* dst = which == 0 ? w2T : (which == 1 ? w3T : w4T);
    dst[r] = f2bf(src[(size_t)k * 768 + nrow]);
  }
}

// ---------------- aggregation: out[n] = h[n] + sum_{e in(n)} h[src[e]] ------
// 256-thread blocks, 4 nodes/block (wave per node), 16B loads.
template <int KK>
__global__ __launch_bounds__(256) void k_agg(const unsigned short* __restrict__ h,
                                             const int* __restrict__ rp,
                                             const int* __restrict__ csr,
                                             unsigned short* __restrict__ out) {
  const int node = blockIdx.x * 4 + (threadIdx.x >> 6);
  const int lane = threadIdx.x & 63;
  constexpr int NE = (KK == 512) ? 8 : 12;
  float acc[NE];
  {
    const char* hp = (const char*)(h + (size_t)node * KK);
    uint4 v = *(const uint4*)(hp + lane * 16);
    acc[0] = b2f_lo(v.x); acc[1] = b2f_hi(v.x);
    acc[2] = b2f_lo(v.y); acc[3] = b2f_hi(v.y);
    acc[4] = b2f_lo(v.z); acc[5] = b2f_hi(v.z);
    acc[6] = b2f_lo(v.w); acc[7] = b2f_hi(v.w);
    if (KK == 768) {
      uint2 w = *(const uint2*)(hp + 1024 + lane * 8);
      acc[8] = b2f_lo(w.x); acc[9] = b2f_hi(w.x);
      acc[10] = b2f_lo(w.y); acc[11] = b2f_hi(w.y);
    }
  }
  int s = rp[node], e = rp[node + 1];
  for (int i = s; i < e; ++i) {
    const char* sp = (const char*)(h + (size_t)csr[i] * KK);
    uint4 v = *(const uint4*)(sp + lane * 16);
    acc[0] += b2f_lo(v.x); acc[1] += b2f_hi(v.x);
    acc[2] += b2f_lo(v.y); acc[3] += b2f_hi(v.y);
    acc[4] += b2f_lo(v.z); acc[5] += b2f_hi(v.z);
    acc[6] += b2f_lo(v.w); acc[7] += b2f_hi(v.w);
    if (KK == 768) {
      uint2 w = *(const uint2*)(sp + 1024 + lane * 8);
      acc[8] += b2f_lo(w.x); acc[9] += b2f_hi(w.x);
      acc[10] += b2f_lo(w.y); acc[11] += b2f_hi(w.y);
    }
  }
  char* op = (char*)(out + (size_t)node * KK);
  uint4 v;
  v.x = pack2bf(acc[0], acc[1]); v.y = pack2bf(acc[2], acc[3]);
  v.z = pack2bf(acc[4], acc[5]); v.w = pack2bf(acc[6], acc[7]);
  *(uint4*)(op + lane * 16) = v;
  if (KK == 768) {
    uint2 w;
    w.x = pack2bf(acc[8], acc[9]); w.y = pack2bf(acc[10], acc[11]);
    *(uint2*)(op + 1024 + lane * 8) = w;
  }
}

// ---------------- GEMM: C(M,Nn) = relu(A(M,K) @ Bt(Nn,K)^T + bias) ----------
// A,Bt,C bf16 row-major. Fragment-linear LDS layout (conflict-free, r3).
__global__ __launch_bounds__(256) void k_gemm(const unsigned short* __restrict__ A,
                                              const unsigned short* __restrict__ Bt,
                                              const float* __restrict__ bias,
                                              unsigned short* __restrict__ C,
                                              int M, int K, int Nn) {
  __shared__ __align__(16) unsigned short As[128 * 32];  // 8 tiles x 64 chunks x 16B
  __shared__ __align__(16) unsigned short Bs[128 * 32];
  const int tid = threadIdx.x;
  const int wave = tid >> 6, lane = tid & 63;
  const int m0 = blockIdx.y * 128;
  const int n0 = blockIdx.x * 128;
  const int wr = wave & 1, wc = wave >> 1;
  const int st_row = (lane & 15);       // row within tile
  const int st_kc = lane >> 4;          // k-chunk 0..3

  f32x4 zero = {0.f, 0.f, 0.f, 0.f};
  f32x4 acc[4][4];
  #pragma unroll
  for (int mt = 0; mt < 4; ++mt)
    #pragma unroll
    for (int nt = 0; nt < 4; ++nt) acc[mt][nt] = zero;

  for (int k0 = 0; k0 < K; k0 += 32) {
    __syncthreads();
    #pragma unroll
    for (int j = 0; j < 2; ++j) {
      int tile = wave * 2 + j;                   // 0..7
      int row = tile * 16 + st_row;
      int gm = m0 + row; if (gm >= M) gm = 0;    // clamp: data unused
      gload_lds16(A + (size_t)gm * K + k0 + st_kc * 8,
                  (char*)As + (tile * 64 + lane) * 16);
    }
    #pragma unroll
    for (int j = 0; j < 2; ++j) {
      int tile = wave * 2 + j;
      int row = tile * 16 + st_row;
      gload_lds16(Bt + (size_t)(n0 + row) * K + k0 + st_kc * 8,
                  (char*)Bs + (tile * 64 + lane) * 16);
    }
    __syncthreads();
    bf16x8 af[4], bfr[4];
    #pragma unroll
    for (int mt = 0; mt < 4; ++mt)
      af[mt] = *(const bf16x8*)((const char*)As + ((wr * 4 + mt) * 64 + lane) * 16);
    #pragma unroll
    for (int nt = 0; nt < 4; ++nt)
      bfr[nt] = *(const bf16x8*)((const char*)Bs + ((wc * 4 + nt) * 64 + lane) * 16);
    #pragma unroll
    for (int mt = 0; mt < 4; ++mt)
      #pragma unroll
      for (int nt = 0; nt < 4; ++nt)
        acc[mt][nt] = __builtin_amdgcn_mfma_f32_16x16x32_bf16(af[mt], bfr[nt], acc[mt][nt], 0, 0, 0);
  }

  const int q = lane >> 4, ccol = lane & 15;
  #pragma unroll
  for (int nt = 0; nt < 4; ++nt) {
    int n = n0 + wc * 64 + nt * 16 + ccol;
    float bv = bias[n];
    #pragma unroll
    for (int mt = 0; mt < 4; ++mt) {
      int mbase = m0 + wr * 64 + mt * 16 + q * 4;
      #pragma unroll
      for (int r = 0; r < 4; ++r) {
        int m = mbase + r;
        if (m < M) {
          float v = acc[mt][nt][r] + bv;
          v = v > 0.f ? v : 0.f;
          C[(size_t)m * Nn + n] = f2bf(v);
        }
      }
    }
  }
}

// ---------------- pool phase 1: per-graph sums (grid-wide, sorted batch) ----
__global__ __launch_bounds__(256) void k_pool1(const unsigned short* __restrict__ h,
                                               const int* __restrict__ batch,
                                               float* __restrict__ sums,
                                               int* __restrict__ cnt) {
  const int tid = threadIdx.x;
  const int n0 = blockIdx.x * 128;
  const int n1 = min(n0 + 128, NN);
  int curg = batch[n0];
  float a0 = 0.f, a1 = 0.f, a2 = 0.f;
  int c = 0;
  for (int n = n0; n < n1; ++n) {
    int g = batch[n];  // uniform across block
    if (g != curg) {
      atomicAdd(&sums[curg * EMBD + tid], a0);
      atomicAdd(&sums[curg * EMBD + tid + 256], a1);
      atomicAdd(&sums[curg * EMBD + tid + 512], a2);
      if (tid == 0) atomicAdd(&cnt[curg], c);
      a0 = a1 = a2 = 0.f; c = 0; curg = g;
    }
    const unsigned short* hp = h + (size_t)n * EMBD;
    a0 += b2f(hp[tid]); a1 += b2f(hp[tid + 256]); a2 += b2f(hp[tid + 512]);
    ++c;
  }
  atomicAdd(&sums[curg * EMBD + tid], a0);
  atomicAdd(&sums[curg * EMBD + tid + 256], a1);
  atomicAdd(&sums[curg * EMBD + tid + 512], a2);
  if (tid == 0) atomicAdd(&cnt[curg], c);
}

// ---------------- pool phase 2: dense 768->4 + log_softmax ------------------
__global__ __launch_bounds__(64) void k_pool2(const float* __restrict__ sums,
                                              const int* __restrict__ cnt,
                                              const float* __restrict__ dw,
                                              const float* __restrict__ db,
                                              float* __restrict__ outp) {
  int g = blockIdx.x, lane = threadIdx.x;
  float inv = 1.f / fmaxf((float)cnt[g], 1.f);
  float po[4] = {0.f, 0.f, 0.f, 0.f};
  #pragma unroll
  for (int i = 0; i < 12; ++i) {
    int f = lane + i * 64;
    float pv = sums[g * EMBD + f] * inv;
    #pragma unroll
    for (int o = 0; o < 4; ++o) po[o] += pv * dw[f * 4 + o];
  }
  #pragma unroll
  for (int o = 0; o < 4; ++o) {
    #pragma unroll
    for (int s = 1; s < 64; s <<= 1) po[o] += __shfl_xor(po[o], s);
  }
  if (lane == 0) {
    float l[4], m = -1e30f;
    #pragma unroll
    for (int o = 0; o < 4; ++o) { l[o] = po[o] + db[o]; m = fmaxf(m, l[o]); }
    float sum = 0.f;
    #pragma unroll
    for (int o = 0; o < 4; ++o) sum += expf(l[o] - m);
    float lse = m + logf(sum);
    #pragma unroll
    for (int o = 0; o < 4; ++o) outp[g * 4 + o] = l[o] - lse;
  }
}

// ---------------- launch ----------------------------------------------------
extern "C" void kernel_launch(void* const* d_in, const int* in_sizes, int n_in,
                              void* d_out, int out_size, void* d_ws, size_t ws_size,
                              hipStream_t stream) {
  const float* x        = (const float*)d_in[0];
  const int*   ei       = (const int*)d_in[1];
  const int*   batch    = (const int*)d_in[2];
  const float* conv0_w  = (const float*)d_in[3];
  const float* bn0_g    = (const float*)d_in[4];
  const float* bn0_b    = (const float*)d_in[5];
  const float* bn0_m    = (const float*)d_in[6];
  const float* bn0_v    = (const float*)d_in[7];
  const float* conv1_w  = (const float*)d_in[8];
  const float* conv2_w  = (const float*)d_in[9];
  const float* bn2_g    = (const float*)d_in[10];
  const float* bn2_b    = (const float*)d_in[11];
  const float* bn2_m    = (const float*)d_in[12];
  const float* bn2_v    = (const float*)d_in[13];
  const float* g1w1 = (const float*)d_in[14];
  const float* g1b1 = (const float*)d_in[15];
  const float* g1w2 = (const float*)d_in[16];
  const float* g1b2 = (const float*)d_in[17];
  const float* g2w1 = (const float*)d_in[18];
  const float* g2b1 = (const float*)d_in[19];
  const float* g2w2 = (const float*)d_in[20];
  const float* g2b2 = (const float*)d_in[21];
  const float* dw   = (const float*)d_in[22];
  const float* db   = (const float*)d_in[23];

  char* base = (char*)d_ws;
  unsigned short* h0 = (unsigned short*)(base);
  unsigned short* a2 = (unsigned short*)(base);
  unsigned short* a1 = (unsigned short*)(base + 20480000ull);
  unsigned short* z  = (unsigned short*)(base + 40960000ull);
  unsigned short* h1 = (unsigned short*)(base + 71680000ull);
  unsigned short* h2 = h1;
  size_t off = 102400000ull;
  unsigned short* w1T = (unsigned short*)(base + off); off += 786432ull;    // 768x512
  unsigned short* w2T = (unsigned short*)(base + off); off += 1179648ull;   // 768x768
  unsigned short* w3T = (unsigned short*)(base + off); off += 1179648ull;
  unsigned short* w4T = (unsigned short*)(base + off); off += 1179648ull;
  // deg, sums, cnt contiguous -> single memset
  int*   deg     = (int*)(base + off);   off += 80000ull;
  float* sums    = (float*)(base + off); off += 196608ull;   // 64*768 f32
  int*   cnt     = (int*)(base + off);   off += 256ull;
  int*   row_ptr = (int*)(base + off);   off += 80128ull;
  int*   cursor  = (int*)(base + off);   off += 80128ull;
  int*   csr_src = (int*)(base + off);   off += 1280000ull;

  hipMemsetAsync(deg, 0, 80000ull + 196608ull + 256ull, stream);

  k_conv<<<NN / 4, 256, 0, stream>>>(x, conv0_w, bn0_g, bn0_b, bn0_m, bn0_v,
                                     conv1_w, conv2_w, bn2_g, bn2_b, bn2_m, bn2_v, h0);

  k_count<<<(EE + 255) / 256, 256, 0, stream>>>(ei, deg);
  k_scan<<<1, 1024, 0, stream>>>(deg, row_ptr, cursor, NN);
  k_scatter<<<(EE + 255) / 256, 256, 0, stream>>>(ei, cursor, csr_src);

  k_trans_all<<<8448, 256, 0, stream>>>(g1w1, g1w2, g2w1, g2w2, w1T, w2T, w3T, w4T);

  dim3 ggrid(6, 157);

  // GIN1
  k_agg<512><<<NN / 4, 256, 0, stream>>>(h0, row_ptr, csr_src, a1);
  k_gemm<<<ggrid, 256, 0, stream>>>(a1, w1T, g1b1, z, NN, 512, 768);
  k_gemm<<<ggrid, 256, 0, stream>>>(z, w2T, g1b2, h1, NN, 768, 768);
  // GIN2
  k_agg<768><<<NN / 4, 256, 0, stream>>>(h1, row_ptr, csr_src, a2);
  k_gemm<<<ggrid, 256, 0, stream>>>(a2, w3T, g2b1, z, NN, 768, 768);
  k_gemm<<<ggrid, 256, 0, stream>>>(z, w4T, g2b2, h2, NN, 768, 768);

  k_pool1<<<(NN + 127) / 128, 256, 0, stream>>>(h2, batch, sums, cnt);
  k_pool2<<<GG, 64, 0, stream>>>(sums, cnt, dw, db, (float*)d_out);
}

// Round 6
// 748.855 us; speedup vs baseline: 1.2245x; 1.2245x over previous
//
#include <hip/hip_runtime.h>
#include <cstdint>

#define NN 20000
#define TT 256
#define EE 320000
#define GG 64
#define EMBD 768
#define FIND 512

typedef __bf16 bf16x8 __attribute__((ext_vector_type(8)));
typedef float f32x4 __attribute__((ext_vector_type(4)));

__device__ __forceinline__ float b2f(unsigned short u) {
  union { unsigned int i; float f; } v; v.i = ((unsigned int)u) << 16; return v.f;
}
__device__ __forceinline__ float b2f_lo(unsigned int u) {
  union { unsigned int i; float f; } v; v.i = u << 16; return v.f;
}
__device__ __forceinline__ float b2f_hi(unsigned int u) {
  union { unsigned int i; float f; } v; v.i = u & 0xFFFF0000u; return v.f;
}
__device__ __forceinline__ unsigned short f2bf(float f) {
  union { float f; unsigned int i; } v; v.f = f;
  unsigned int u = v.i;
  return (unsigned short)((u + 0x7FFFu + ((u >> 16) & 1u)) >> 16);
}
__device__ __forceinline__ unsigned int pack2bf(float lo, float hi) {
  return (unsigned int)f2bf(lo) | ((unsigned int)f2bf(hi) << 16);
}

// async global->LDS, 16B per lane. LDS dest is wave-uniform base + lane*16.
__device__ __forceinline__ void gload_lds16(const void* g, void* l) {
  auto gp = reinterpret_cast<const __attribute__((address_space(1))) char*>(
      reinterpret_cast<uintptr_t>(g));
  auto lp = reinterpret_cast<__attribute__((address_space(3))) char*>(
      (unsigned int)(reinterpret_cast<uintptr_t>(l)));
  __builtin_amdgcn_global_load_lds(gp, lp, 16, 0, 0);
}

// ---------------- fused temporal conv stack: x(N,256) -> h0 bf16 (N,512) ----
// FROZEN: exact r1/r4 structure, measured 181 us twice. Do not restructure —
// two attempts (r3 channel-outer, r5 swizzle+k-outer) both regressed to
// 300-400 us despite "better" theory.
__global__ __launch_bounds__(256, 3) void k_conv(
    const float* __restrict__ x,
    const float* __restrict__ w0, const float* __restrict__ g0,
    const float* __restrict__ be0, const float* __restrict__ mu0,
    const float* __restrict__ va0,
    const float* __restrict__ w1, const float* __restrict__ w2,
    const float* __restrict__ g2, const float* __restrict__ be2,
    const float* __restrict__ mu2, const float* __restrict__ va2,
    unsigned short* __restrict__ out) {
  __shared__ float xs[4][288];        // idx = t + 16, t in [-16, 271]
  __shared__ float h0s[4][8][288];    // [node][ch][t + 12], t in [-12, 275]
  const int tid = threadIdx.x;
  const int wv = tid >> 6;            // node slot within block
  const int l = tid & 63;             // lane; handles t = 4l .. 4l+3
  const int n = blockIdx.x * 4 + wv;

  // stage x + zero halos
  float4 xv4 = *(const float4*)(x + (size_t)n * TT + 4 * l);
  *(float4*)&xs[wv][16 + 4 * l] = xv4;
  float4 z4 = make_float4(0.f, 0.f, 0.f, 0.f);
  if (l < 4) *(float4*)&xs[wv][4 * l] = z4;
  else if (l < 8) *(float4*)&xs[wv][272 + 4 * (l - 4)] = z4;
  __syncthreads();

  // conv0 (k=33, 1->8): window floats [4l, 4l+35]
  float win[36];
  #pragma unroll
  for (int i = 0; i < 9; ++i)
    *(float4*)&win[4 * i] = *(const float4*)&xs[wv][4 * l + 4 * i];
  float c0[4][8];
  #pragma unroll
  for (int j = 0; j < 4; ++j)
    #pragma unroll
    for (int c = 0; c < 8; ++c) c0[j][c] = 0.f;
  #pragma unroll
  for (int w = 0; w < 33; ++w) {
    #pragma unroll
    for (int c = 0; c < 8; ++c) {
      float wt = w0[w * 8 + c];            // uniform -> s_load
      #pragma unroll
      for (int j = 0; j < 4; ++j) c0[j][c] += win[w + j] * wt;
    }
  }
  // bn0 + store to channel-major LDS
  #pragma unroll
  for (int c = 0; c < 8; ++c) {
    float s = g0[c] * rsqrtf(va0[c] + 1e-5f);
    float o = be0[c] - mu0[c] * s;
    float4 v;
    v.x = c0[0][c] * s + o; v.y = c0[1][c] * s + o;
    v.z = c0[2][c] * s + o; v.w = c0[3][c] * s + o;
    *(float4*)&h0s[wv][c][12 + 4 * l] = v;
  }
  // zero halos of h0 rows: idx [0,12) and [268,288)
  if (l < 3) {
    #pragma unroll
    for (int c = 0; c < 8; ++c) *(float4*)&h0s[wv][c][4 * l] = z4;
  } else if (l < 8) {
    #pragma unroll
    for (int c = 0; c < 8; ++c) *(float4*)&h0s[wv][c][268 + 4 * (l - 3)] = z4;
  }
  __syncthreads();

  // conv1 depthwise (k=21) + relu, then conv2 pointwise (8->16)
  float p[4][16];
  #pragma unroll
  for (int j = 0; j < 4; ++j)
    #pragma unroll
    for (int k = 0; k < 16; ++k) p[j][k] = 0.f;
  #pragma unroll
  for (int c = 0; c < 8; ++c) {
    float hw[28];  // floats [4l, 4l+27] = t' in [4l-12, 4l+15]
    #pragma unroll
    for (int i = 0; i < 7; ++i)
      *(float4*)&hw[4 * i] = *(const float4*)&h0s[wv][c][4 * l + 4 * i];
    float d[4];
    #pragma unroll
    for (int j = 0; j < 4; ++j) {
      float a = 0.f;
      #pragma unroll
      for (int w = 0; w < 21; ++w) a += hw[j + w + 2] * w1[w * 8 + c];
      d[j] = fmaxf(a, 0.f);
    }
    #pragma unroll
    for (int k = 0; k < 16; ++k) {
      float wt = w2[c * 16 + k];
      #pragma unroll
      for (int j = 0; j < 4; ++j) p[j][k] += d[j] * wt;
    }
  }
  // bn2 + relu + mean-pool over 8 t (4 in-thread + lane pair)
  #pragma unroll
  for (int k = 0; k < 16; ++k) {
    float s = g2[k] * rsqrtf(va2[k] + 1e-5f);
    float o = be2[k] - mu2[k] * s;
    float v = 0.f;
    #pragma unroll
    for (int j = 0; j < 4; ++j) v += fmaxf(p[j][k] * s + o, 0.f);
    v += __shfl_xor(v, 1);
    p[0][k] = v * 0.125f;
  }
  if ((l & 1) == 0) {
    int grp = l >> 1;  // pool group 0..31
    unsigned short* op = out + (size_t)n * FIND + grp * 16;
    #pragma unroll
    for (int q = 0; q < 4; ++q) {
      ushort4 v;
      v.x = f2bf(p[0][q * 4 + 0]); v.y = f2bf(p[0][q * 4 + 1]);
      v.z = f2bf(p[0][q * 4 + 2]); v.w = f2bf(p[0][q * 4 + 3]);
      *(ushort4*)(op + q * 4) = v;
    }
  }
}

// ---------------- fused init: edge-count histogram + weight transposes ------
__global__ void k_init(const int* __restrict__ ei, int* __restrict__ deg,
                       const float* __restrict__ g1w1, const float* __restrict__ g1w2,
                       const float* __restrict__ g2w1, const float* __restrict__ g2w2,
                       unsigned short* __restrict__ w1T, unsigned short* __restrict__ w2T,
                       unsigned short* __restrict__ w3T, unsigned short* __restrict__ w4T) {
  int b = blockIdx.x;
  if (b < 1250) {                     // count: 1250*256 >= EE
    int e = b * 256 + threadIdx.x;
    if (e < EE) atomicAdd(&deg[ei[EE + e]], 1);
  } else {
    int i = (b - 1250) * 256 + threadIdx.x;
    if (i < 393216) {                 // 768 x 512 (K=512)
      int nrow = i >> 9, k = i & 511;
      w1T[i] = f2bf(g1w1[(size_t)k * 768 + nrow]);
    } else {
      int j = i - 393216;
      int which = j / 589824;         // 0..2, 768 x 768 each
      int r = j - which * 589824;
      int nrow = r / 768, k = r - nrow * 768;
      const float* src = which == 0 ? g1w2 : (which == 1 ? g2w1 : g2w2);
      unsigned short* dst = which == 0 ? w2T : (which == 1 ? w3T : w4T);
      dst[r] = f2bf(src[(size_t)k * 768 + nrow]);
    }
  }
}

// ---------------- scan: register-serial, 20 elems/thread, one block ---------
__global__ __launch_bounds__(1024) void k_scan(const int* __restrict__ deg,
                                               int* __restrict__ row_ptr,
                                               int* __restrict__ cursor) {
  __shared__ int wsums[16];
  const int tid = threadIdx.x, lane = tid & 63, wid = tid >> 6;
  const int base = tid * 20;
  int v[20];
  int s = 0;
  #pragma unroll
  for (int i = 0; i < 20; ++i) {
    int idx = base + i;
    int d = (idx < NN) ? deg[idx] : 0;
    v[i] = s;                // local exclusive prefix
    s += d;
  }
  int inc = s;
  #pragma unroll
  for (int off = 1; off < 64; off <<= 1) {
    int t = __shfl_up(inc, off);
    if (lane >= off) inc += t;
  }
  if (lane == 63) wsums[wid] = inc;
  __syncthreads();
  if (wid == 0) {
    int ws = (lane < 16) ? wsums[lane] : 0;
    #pragma unroll
    for (int off = 1; off < 16; off <<= 1) {
      int t = __shfl_up(ws, off);
      if (lane >= off) ws += t;
    }
    if (lane < 16) wsums[lane] = ws;   // inclusive wave-sum prefix
    if (lane == 15) row_ptr[NN] = ws;  // grand total
  }
  __syncthreads();
  int woff = (wid > 0) ? wsums[wid - 1] : 0;
  int texcl = woff + inc - s;
  #pragma unroll
  for (int i = 0; i < 20; ++i) {
    int idx = base + i;
    if (idx < NN) { int e = texcl + v[i]; row_ptr[idx] = e; cursor[idx] = e; }
  }
}

__global__ void k_scatter(const int* __restrict__ ei, int* __restrict__ cursor,
                          int* __restrict__ csr_src) {
  int e = blockIdx.x * 256 + threadIdx.x;
  if (e < EE) {
    int d = ei[EE + e];
    int pos = atomicAdd(&cursor[d], 1);
    csr_src[pos] = ei[e];
  }
}

// ---------------- aggregation: out[n] = h[n] + sum_{e in(n)} h[src[e]] ------
// 256-thread blocks, 4 nodes/block (wave per node), 16B loads.
template <int KK>
__global__ __launch_bounds__(256) void k_agg(const unsigned short* __restrict__ h,
                                             const int* __restrict__ rp,
                                             const int* __restrict__ csr,
                                             unsigned short* __restrict__ out) {
  const int node = blockIdx.x * 4 + (threadIdx.x >> 6);
  const int lane = threadIdx.x & 63;
  constexpr int NE = (KK == 512) ? 8 : 12;
  float acc[NE];
  {
    const char* hp = (const char*)(h + (size_t)node * KK);
    uint4 v = *(const uint4*)(hp + lane * 16);
    acc[0] = b2f_lo(v.x); acc[1] = b2f_hi(v.x);
    acc[2] = b2f_lo(v.y); acc[3] = b2f_hi(v.y);
    acc[4] = b2f_lo(v.z); acc[5] = b2f_hi(v.z);
    acc[6] = b2f_lo(v.w); acc[7] = b2f_hi(v.w);
    if (KK == 768) {
      uint2 w = *(const uint2*)(hp + 1024 + lane * 8);
      acc[8] = b2f_lo(w.x); acc[9] = b2f_hi(w.x);
      acc[10] = b2f_lo(w.y); acc[11] = b2f_hi(w.y);
    }
  }
  int s = rp[node], e = rp[node + 1];
  for (int i = s; i < e; ++i) {
    const char* sp = (const char*)(h + (size_t)csr[i] * KK);
    uint4 v = *(const uint4*)(sp + lane * 16);
    acc[0] += b2f_lo(v.x); acc[1] += b2f_hi(v.x);
    acc[2] += b2f_lo(v.y); acc[3] += b2f_hi(v.y);
    acc[4] += b2f_lo(v.z); acc[5] += b2f_hi(v.z);
    acc[6] += b2f_lo(v.w); acc[7] += b2f_hi(v.w);
    if (KK == 768) {
      uint2 w = *(const uint2*)(sp + 1024 + lane * 8);
      acc[8] += b2f_lo(w.x); acc[9] += b2f_hi(w.x);
      acc[10] += b2f_lo(w.y); acc[11] += b2f_hi(w.y);
    }
  }
  char* op = (char*)(out + (size_t)node * KK);
  uint4 v;
  v.x = pack2bf(acc[0], acc[1]); v.y = pack2bf(acc[2], acc[3]);
  v.z = pack2bf(acc[4], acc[5]); v.w = pack2bf(acc[6], acc[7]);
  *(uint4*)(op + lane * 16) = v;
  if (KK == 768) {
    uint2 w;
    w.x = pack2bf(acc[8], acc[9]); w.y = pack2bf(acc[10], acc[11]);
    *(uint2*)(op + 1024 + lane * 8) = w;
  }
}

// ---------------- GEMM: C(M,Nn) = relu(A(M,K) @ Bt(Nn,K)^T + bias) ----------
// A,Bt,C bf16 row-major. BK=64: 32 MFMA per barrier pair (2x fewer syncs than
// BK=32 — K is only 512/768 so barrier overhead matters). Fragment-linear LDS
// (conflict-free). LDS 32 KB total -> 5 blocks/CU.
__global__ __launch_bounds__(256) void k_gemm(const unsigned short* __restrict__ A,
                                              const unsigned short* __restrict__ Bt,
                                              const float* __restrict__ bias,
                                              unsigned short* __restrict__ C,
                                              int M, int K, int Nn) {
  // chunk c in [0,128) within a 16-row tile: row = c&15, koff = (c>>4)*8
  __shared__ __align__(16) unsigned short As[128 * 64];  // 8 tiles x 128 chunks x 16B
  __shared__ __align__(16) unsigned short Bs[128 * 64];
  const int tid = threadIdx.x;
  const int wave = tid >> 6, lane = tid & 63;
  const int m0 = blockIdx.y * 128;
  const int n0 = blockIdx.x * 128;
  const int wr = wave & 1, wc = wave >> 1;

  f32x4 zero = {0.f, 0.f, 0.f, 0.f};
  f32x4 acc[4][4];
  #pragma unroll
  for (int mt = 0; mt < 4; ++mt)
    #pragma unroll
    for (int nt = 0; nt < 4; ++nt) acc[mt][nt] = zero;

  for (int k0 = 0; k0 < K; k0 += 64) {
    __syncthreads();
    #pragma unroll
    for (int j = 0; j < 4; ++j) {
      int chunk = (wave * 4 + j) * 64 + lane;    // 0..1023
      int tile = chunk >> 7, c = chunk & 127;
      int row = tile * 16 + (c & 15);
      int koff = (c >> 4) * 8;
      int gm = m0 + row; if (gm >= M) gm = 0;    // clamp: data unused
      gload_lds16(A + (size_t)gm * K + k0 + koff, (char*)As + chunk * 16);
    }
    #pragma unroll
    for (int j = 0; j < 4; ++j) {
      int chunk = (wave * 4 + j) * 64 + lane;
      int tile = chunk >> 7, c = chunk & 127;
      int row = tile * 16 + (c & 15);
      int koff = (c >> 4) * 8;
      gload_lds16(Bt + (size_t)(n0 + row) * K + k0 + koff, (char*)Bs + chunk * 16);
    }
    __syncthreads();
    #pragma unroll
    for (int s = 0; s < 2; ++s) {
      bf16x8 af[4], bfr[4];
      #pragma unroll
      for (int mt = 0; mt < 4; ++mt)
        af[mt] = *(const bf16x8*)((const char*)As +
                                  (((wr * 4 + mt) * 128 + s * 64 + lane) * 16));
      #pragma unroll
      for (int nt = 0; nt < 4; ++nt)
        bfr[nt] = *(const bf16x8*)((const char*)Bs +
                                   (((wc * 4 + nt) * 128 + s * 64 + lane) * 16));
      #pragma unroll
      for (int mt = 0; mt < 4; ++mt)
        #pragma unroll
        for (int nt = 0; nt < 4; ++nt)
          acc[mt][nt] = __builtin_amdgcn_mfma_f32_16x16x32_bf16(af[mt], bfr[nt], acc[mt][nt], 0, 0, 0);
    }
  }

  const int q = lane >> 4, ccol = lane & 15;
  #pragma unroll
  for (int nt = 0; nt < 4; ++nt) {
    int n = n0 + wc * 64 + nt * 16 + ccol;
    float bv = bias[n];
    #pragma unroll
    for (int mt = 0; mt < 4; ++mt) {
      int mbase = m0 + wr * 64 + mt * 16 + q * 4;
      #pragma unroll
      for (int r = 0; r < 4; ++r) {
        int m = mbase + r;
        if (m < M) {
          float v = acc[mt][nt][r] + bv;
          v = v > 0.f ? v : 0.f;
          C[(size_t)m * Nn + n] = f2bf(v);
        }
      }
    }
  }
}

// ---------------- pool phase 1: per-graph sums (grid-wide, sorted batch) ----
__global__ __launch_bounds__(256) void k_pool1(const unsigned short* __restrict__ h,
                                               const int* __restrict__ batch,
                                               float* __restrict__ sums,
                                               int* __restrict__ cnt) {
  const int tid = threadIdx.x;
  const int n0 = blockIdx.x * 128;
  const int n1 = min(n0 + 128, NN);
  int curg = batch[n0];
  float a0 = 0.f, a1 = 0.f, a2 = 0.f;
  int c = 0;
  for (int n = n0; n < n1; ++n) {
    int g = batch[n];  // uniform across block
    if (g != curg) {
      atomicAdd(&sums[curg * EMBD + tid], a0);
      atomicAdd(&sums[curg * EMBD + tid + 256], a1);
      atomicAdd(&sums[curg * EMBD + tid + 512], a2);
      if (tid == 0) atomicAdd(&cnt[curg], c);
      a0 = a1 = a2 = 0.f; c = 0; curg = g;
    }
    const unsigned short* hp = h + (size_t)n * EMBD;
    a0 += b2f(hp[tid]); a1 += b2f(hp[tid + 256]); a2 += b2f(hp[tid + 512]);
    ++c;
  }
  atomicAdd(&sums[curg * EMBD + tid], a0);
  atomicAdd(&sums[curg * EMBD + tid + 256], a1);
  atomicAdd(&sums[curg * EMBD + tid + 512], a2);
  if (tid == 0) atomicAdd(&cnt[curg], c);
}

// ---------------- pool phase 2: dense 768->4 + log_softmax ------------------
__global__ __launch_bounds__(64) void k_pool2(const float* __restrict__ sums,
                                              const int* __restrict__ cnt,
                                              const float* __restrict__ dw,
                                              const float* __restrict__ db,
                                              float* __restrict__ outp) {
  int g = blockIdx.x, lane = threadIdx.x;
  float inv = 1.f / fmaxf((float)cnt[g], 1.f);
  float po[4] = {0.f, 0.f, 0.f, 0.f};
  #pragma unroll
  for (int i = 0; i < 12; ++i) {
    int f = lane + i * 64;
    float pv = sums[g * EMBD + f] * inv;
    #pragma unroll
    for (int o = 0; o < 4; ++o) po[o] += pv * dw[f * 4 + o];
  }
  #pragma unroll
  for (int o = 0; o < 4; ++o) {
    #pragma unroll
    for (int s = 1; s < 64; s <<= 1) po[o] += __shfl_xor(po[o], s);
  }
  if (lane == 0) {
    float l[4], m = -1e30f;
    #pragma unroll
    for (int o = 0; o < 4; ++o) { l[o] = po[o] + db[o]; m = fmaxf(m, l[o]); }
    float sum = 0.f;
    #pragma unroll
    for (int o = 0; o < 4; ++o) sum += expf(l[o] - m);
    float lse = m + logf(sum);
    #pragma unroll
    for (int o = 0; o < 4; ++o) outp[g * 4 + o] = l[o] - lse;
  }
}

// ---------------- launch ----------------------------------------------------
extern "C" void kernel_launch(void* const* d_in, const int* in_sizes, int n_in,
                              void* d_out, int out_size, void* d_ws, size_t ws_size,
                              hipStream_t stream) {
  const float* x        = (const float*)d_in[0];
  const int*   ei       = (const int*)d_in[1];
  const int*   batch    = (const int*)d_in[2];
  const float* conv0_w  = (const float*)d_in[3];
  const float* bn0_g    = (const float*)d_in[4];
  const float* bn0_b    = (const float*)d_in[5];
  const float* bn0_m    = (const float*)d_in[6];
  const float* bn0_v    = (const float*)d_in[7];
  const float* conv1_w  = (const float*)d_in[8];
  const float* conv2_w  = (const float*)d_in[9];
  const float* bn2_g    = (const float*)d_in[10];
  const float* bn2_b    = (const float*)d_in[11];
  const float* bn2_m    = (const float*)d_in[12];
  const float* bn2_v    = (const float*)d_in[13];
  const float* g1w1 = (const float*)d_in[14];
  const float* g1b1 = (const float*)d_in[15];
  const float* g1w2 = (const float*)d_in[16];
  const float* g1b2 = (const float*)d_in[17];
  const float* g2w1 = (const float*)d_in[18];
  const float* g2b1 = (const float*)d_in[19];
  const float* g2w2 = (const float*)d_in[20];
  const float* g2b2 = (const float*)d_in[21];
  const float* dw   = (const float*)d_in[22];
  const float* db   = (const float*)d_in[23];

  char* base = (char*)d_ws;
  unsigned short* h0 = (unsigned short*)(base);
  unsigned short* a2 = (unsigned short*)(base);
  unsigned short* a1 = (unsigned short*)(base + 20480000ull);
  unsigned short* z  = (unsigned short*)(base + 40960000ull);
  unsigned short* h1 = (unsigned short*)(base + 71680000ull);
  unsigned short* h2 = h1;
  size_t off = 102400000ull;
  unsigned short* w1T = (unsigned short*)(base + off); off += 786432ull;    // 768x512
  unsigned short* w2T = (unsigned short*)(base + off); off += 1179648ull;   // 768x768
  unsigned short* w3T = (unsigned short*)(base + off); off += 1179648ull;
  unsigned short* w4T = (unsigned short*)(base + off); off += 1179648ull;
  // deg, sums, cnt contiguous -> single memset
  int*   deg     = (int*)(base + off);   off += 80000ull;
  float* sums    = (float*)(base + off); off += 196608ull;   // 64*768 f32
  int*   cnt     = (int*)(base + off);   off += 256ull;
  int*   row_ptr = (int*)(base + off);   off += 80128ull;
  int*   cursor  = (int*)(base + off);   off += 80128ull;
  int*   csr_src = (int*)(base + off);   off += 1280000ull;

  hipMemsetAsync(deg, 0, 80000ull + 196608ull + 256ull, stream);

  k_conv<<<NN / 4, 256, 0, stream>>>(x, conv0_w, bn0_g, bn0_b, bn0_m, bn0_v,
                                     conv1_w, conv2_w, bn2_g, bn2_b, bn2_m, bn2_v, h0);

  k_init<<<1250 + 8448, 256, 0, stream>>>(ei, deg, g1w1, g1w2, g2w1, g2w2,
                                          w1T, w2T, w3T, w4T);
  k_scan<<<1, 1024, 0, stream>>>(deg, row_ptr, cursor);
  k_scatter<<<(EE + 255) / 256, 256, 0, stream>>>(ei, cursor, csr_src);

  dim3 ggrid(6, 157);

  // GIN1
  k_agg<512><<<NN / 4, 256, 0, stream>>>(h0, row_ptr, csr_src, a1);
  k_gemm<<<ggrid, 256, 0, stream>>>(a1, w1T, g1b1, z, NN, 512, 768);
  k_gemm<<<ggrid, 256, 0, stream>>>(z, w2T, g1b2, h1, NN, 768, 768);
  // GIN2
  k_agg<768><<<NN / 4, 256, 0, stream>>>(h1, row_ptr, csr_src, a2);
  k_gemm<<<ggrid, 256, 0, stream>>>(a2, w3T, g2b1, z, NN, 768, 768);
  k_gemm<<<ggrid, 256, 0, stream>>>(z, w4T, g2b2, h2, NN, 768, 768);

  k_pool1<<<(NN + 127) / 128, 256, 0, stream>>>(h2, batch, sums, cnt);
  k_pool2<<<GG, 64, 0, stream>>>(sums, cnt, dw, db, (float*)d_out);
}